// Round 14
// baseline (1311.658 us; speedup 1.0000x reference)
//
#include <hip/hip_runtime.h>
#include <cstdint>

#define DEVI __device__ __forceinline__

typedef short v8s __attribute__((ext_vector_type(8)));
typedef float v4f __attribute__((ext_vector_type(4)));

DEVI short f2bf(float f){
  uint32_t u = __builtin_bit_cast(uint32_t, f);
  u += 0x7FFF + ((u >> 16) & 1);          // round-to-nearest-even
  return (short)(u >> 16);
}
DEVI float bf2f(short s){
  uint32_t u = ((uint32_t)(uint16_t)s) << 16;
  return __builtin_bit_cast(float, u);
}
DEVI uint32_t pk2(float a, float b){
  return (uint32_t)(uint16_t)f2bf(a) | ((uint32_t)(uint16_t)f2bf(b) << 16);
}

DEVI void gload16(const void* g, void* l){
  __builtin_amdgcn_global_load_lds(
      (const __attribute__((address_space(1))) unsigned*)g,
      (__attribute__((address_space(3))) unsigned*)l, 16, 0, 0);
}

// ---------------------------------------------------------------- LayerNorm
__global__ __launch_bounds__(256) void ln_kernel(
    const float* __restrict__ x, const float* __restrict__ w,
    const float* __restrict__ b, void* __restrict__ out)
{
  const int row = blockIdx.x;
  const int t = threadIdx.x;
  const float4 v = ((const float4*)(x + (size_t)row * 1024))[t];
  float s  = v.x + v.y + v.z + v.w;
  float s2 = v.x*v.x + v.y*v.y + v.z*v.z + v.w*v.w;
  #pragma unroll
  for (int m = 1; m < 64; m <<= 1){ s += __shfl_xor(s, m); s2 += __shfl_xor(s2, m); }
  __shared__ float ps[4], ps2[4];
  if ((t & 63) == 0){ ps[t >> 6] = s; ps2[t >> 6] = s2; }
  __syncthreads();
  s  = ps[0] + ps[1] + ps[2] + ps[3];
  s2 = ps2[0] + ps2[1] + ps2[2] + ps2[3];
  const float mu = s * (1.f / 1024.f);
  const float rs = rsqrtf(s2 * (1.f / 1024.f) - mu * mu + 1e-5f);
  const float4 wv = ((const float4*)w)[t];
  const float4 bv = ((const float4*)b)[t];
  uint2 pk;
  pk.x = pk2((v.x - mu) * rs * wv.x + bv.x, (v.y - mu) * rs * wv.y + bv.y);
  pk.y = pk2((v.z - mu) * rs * wv.z + bv.z, (v.w - mu) * rs * wv.w + bv.w);
  ((uint2*)out)[(size_t)row * 256 + t] = pk;
}

// ------------- split-K reduce + residual + bias, fused with LayerNorm.
template<int S, bool FIN>
__global__ __launch_bounds__(256) void reduce_ln(
    const float* __restrict__ part, const float* __restrict__ resid,
    const float* __restrict__ bias, float* __restrict__ xout,
    const float* __restrict__ lw, const float* __restrict__ lb,
    void* __restrict__ hout)
{
  const int row = blockIdx.x;
  const int t = threadIdx.x;
  float4 v = ((const float4*)(resid + (size_t)row * 1024))[t];
  const float4 bz = ((const float4*)bias)[t];
  v.x += bz.x; v.y += bz.y; v.z += bz.z; v.w += bz.w;
  #pragma unroll
  for (int s = 0; s < S; ++s){
    const float4 pv = ((const float4*)(part + ((size_t)s * 2048 + row) * 1024))[t];
    v.x += pv.x; v.y += pv.y; v.z += pv.z; v.w += pv.w;
  }
  ((float4*)(xout + (size_t)row * 1024))[t] = v;
  float s  = v.x + v.y + v.z + v.w;
  float s2 = v.x*v.x + v.y*v.y + v.z*v.z + v.w*v.w;
  #pragma unroll
  for (int m = 1; m < 64; m <<= 1){ s += __shfl_xor(s, m); s2 += __shfl_xor(s2, m); }
  __shared__ float ps[4], ps2[4];
  if ((t & 63) == 0){ ps[t >> 6] = s; ps2[t >> 6] = s2; }
  __syncthreads();
  s  = ps[0] + ps[1] + ps[2] + ps[3];
  s2 = ps2[0] + ps2[1] + ps2[2] + ps2[3];
  const float mu = s * (1.f / 1024.f);
  const float rs = rsqrtf(s2 * (1.f / 1024.f) - mu * mu + 1e-5f);
  const float4 wv = ((const float4*)lw)[t];
  const float4 bv = ((const float4*)lb)[t];
  const float o0 = (v.x - mu) * rs * wv.x + bv.x;
  const float o1 = (v.y - mu) * rs * wv.y + bv.y;
  const float o2 = (v.z - mu) * rs * wv.z + bv.z;
  const float o3 = (v.w - mu) * rs * wv.w + bv.w;
  if (FIN){
    ((float4*)hout)[(size_t)row * 256 + t] = make_float4(o0, o1, o2, o3);
  } else {
    uint2 pk;
    pk.x = pk2(o0, o1);
    pk.y = pk2(o2, o3);
    ((uint2*)hout)[(size_t)row * 256 + t] = pk;
  }
}

// ---------------- all weights fp32[K][N] -> bf16[N][K] in ONE dispatch.
// k-fastest job order: consecutive blocks handle adjacent k-tiles of the SAME
// n-rows, so their 128B write segments are adjacent in the output rows ->
// L2/MC can merge into large DRAM bursts.
__global__ __launch_bounds__(256) void wconv_all(
    const float* __restrict__ Wq, const float* __restrict__ Wk,
    const float* __restrict__ Wv, const float* __restrict__ Wp,
    const float* __restrict__ W1, const float* __restrict__ W2,
    short* __restrict__ wtQKV, short* __restrict__ wtP,
    short* __restrict__ wt1, short* __restrict__ wt2)
{
  const int j = blockIdx.x;
  const size_t l = blockIdx.y;
  const size_t S1M = 1048576, S3M = 3145728, S4M = 4194304;
  const float* W; short* Wt; int K, N, n0, k0;
  if (j < 1024){
    const int which = j >> 8, jj = j & 255;        // 16k x 16n, k-fastest
    k0 = (jj & 15) * 64; n0 = (jj >> 4) * 64; K = 1024; N = 1024;
    if (which == 0){ W = Wq + l * S1M; Wt = wtQKV + l * S3M; }
    else if (which == 1){ W = Wk + l * S1M; Wt = wtQKV + l * S3M + S1M; }
    else if (which == 2){ W = Wv + l * S1M; Wt = wtQKV + l * S3M + 2 * S1M; }
    else { W = Wp + l * S1M; Wt = wtP + l * S1M; }
  } else if (j < 2048){
    const int jj = j - 1024;                       // 16k x 64n, k-fastest
    k0 = (jj & 15) * 64; n0 = (jj >> 4) * 64; K = 1024; N = 4096;
    W = W1 + l * S4M; Wt = wt1 + l * S4M;
  } else {
    const int jj = j - 2048;                       // 64k x 16n, k-fastest
    k0 = (jj & 63) * 64; n0 = (jj >> 6) * 64; K = 4096; N = 1024;
    W = W2 + l * S4M; Wt = wt2 + l * S4M;
  }
  __shared__ float t[64][65];
  const int tid = threadIdx.x;
  const int c4 = (tid & 15) * 4, r = tid >> 4;
  #pragma unroll
  for (int i = 0; i < 4; ++i){
    const float4 v = *(const float4*)(W + (size_t)(k0 + r + i*16) * N + n0 + c4);
    t[r + i*16][c4 + 0] = v.x;
    t[r + i*16][c4 + 1] = v.y;
    t[r + i*16][c4 + 2] = v.z;
    t[r + i*16][c4 + 3] = v.w;
  }
  __syncthreads();
  const int k8 = (tid & 7) * 8;
  #pragma unroll
  for (int pass = 0; pass < 2; ++pass){
    const int n = (tid >> 3) + pass * 32;
    v8s s;
    #pragma unroll
    for (int jj = 0; jj < 8; ++jj) s[jj] = f2bf(t[k8 + jj][n]);
    *(v8s*)(Wt + (size_t)(n0 + n) * K + k0 + k8) = s;
  }
}

// ---------------------------------------------------------------- GEMM 128x128
// m97 geometry restored: 256 thr = 4 waves (2x2 of 64x64 out, acc[4][4]),
// SINGLE-buffer 32.8 KB LDS, __launch_bounds__(256,3) -> 3 blocks/CU.
// 64 FLOP per HBM byte, 32 MFMA per wave-K-step (2x gemm5). Latency hiding
// from co-resident blocks (m114); loop = sync; stage; sync; compute.
// T1 n-fastest XCD chunks; T2 XOR-swizzle. Split-K via z (EPI 3 -> partials).
// EPI 0: bf16 = acc + qkv-bias(b0/b1/b2 by 1024-col segment)
// EPI 2: bf16 = gelu(acc + b0[col])
// EPI 3: fp32 partial (no bias) at out + z*M*N
template<int EPI>
__global__ __launch_bounds__(256, 3) void gemm6(
    const short* __restrict__ A, const short* __restrict__ Bt,
    void* __restrict__ out,
    const float* __restrict__ b0, const float* __restrict__ b1,
    const float* __restrict__ b2, int M, int N, int K, int kchunk)
{
  __shared__ __attribute__((aligned(16))) short a_t[128 * 64];
  __shared__ __attribute__((aligned(16))) short b_t[128 * 64];
  const int tid = threadIdx.x, l = tid & 63, w = tid >> 6;

  const int gx = gridDim.x;
  const int bid = blockIdx.y * gx + blockIdx.x;
  const int cpx = (gx * gridDim.y) >> 3;
  const int swz = (bid & 7) * cpx + (bid >> 3);
  const int m0 = (swz / gx) * 128, n0 = (swz % gx) * 128;
  const int kt0 = blockIdx.z * kchunk;

  const int lr = l >> 3;                        // staging row within 8-group
  const int scol = ((l & 7) * 16) ^ (lr << 4);  // pre-swizzled source byte col
  const int wm = w >> 1, wn = w & 1;            // wave grid 2x2
  const int fr = l & 15;
  const int rg = l >> 4;
  const int rxor = (fr & 7) << 4;               // read-side XOR (bytes)

  const v4f vz = {0.f, 0.f, 0.f, 0.f};
  v4f acc[4][4];
  #pragma unroll
  for (int i = 0; i < 4; ++i)
    #pragma unroll
    for (int j = 0; j < 4; ++j) acc[i][j] = vz;

  const char* Ab = (const char*)A;
  const char* Bb = (const char*)Bt;
  auto stage = [&](int kt){
    #pragma unroll
    for (int j = 0; j < 4; ++j){                // A+B: 32 rows each per wave
      const int rb = w * 32 + j * 8;
      gload16(Ab + ((size_t)(m0 + rb + lr) * K + kt) * 2 + scol,
              (char*)a_t + rb * 128);
      gload16(Bb + ((size_t)(n0 + rb + lr) * K + kt) * 2 + scol,
              (char*)b_t + rb * 128);
    }
  };

  const int NT = kchunk >> 6;
  for (int t = 0; t < NT; ++t){
    __syncthreads();                  // prior step's LDS reads complete
    stage(kt0 + (t << 6));
    __syncthreads();                  // implicit vmcnt(0): tile resident
    __builtin_amdgcn_s_setprio(1);
    #pragma unroll
    for (int ks = 0; ks < 2; ++ks){
      const int co = ks * 64 + rg * 16;
      v8s af[4], bf[4];
      #pragma unroll
      for (int mf = 0; mf < 4; ++mf)
        af[mf] = *(const v8s*)((char*)a_t + (wm * 64 + mf * 16 + fr) * 128
                               + (co ^ rxor));
      #pragma unroll
      for (int nf = 0; nf < 4; ++nf)
        bf[nf] = *(const v8s*)((char*)b_t + (wn * 64 + nf * 16 + fr) * 128
                               + (co ^ rxor));
      #pragma unroll
      for (int mf = 0; mf < 4; ++mf)
        #pragma unroll
        for (int nf = 0; nf < 4; ++nf)
          acc[mf][nf] = __builtin_amdgcn_mfma_f32_16x16x32_bf16(
              af[mf], bf[nf], acc[mf][nf], 0, 0, 0);
    }
    __builtin_amdgcn_s_setprio(0);
  }

  float* outp = (EPI == 3)
      ? (float*)out + (size_t)blockIdx.z * ((size_t)M * N) : (float*)out;
  #pragma unroll
  for (int mf = 0; mf < 4; ++mf){
    #pragma unroll
    for (int nf = 0; nf < 4; ++nf){
      const int col = n0 + wn * 64 + nf * 16 + fr;
      float bias = 0.f;
      if (EPI == 0)
        bias = col < 1024 ? b0[col] : (col < 2048 ? b1[col - 1024] : b2[col - 2048]);
      else if (EPI == 2)
        bias = b0[col];
      #pragma unroll
      for (int r = 0; r < 4; ++r){
        const int row = m0 + wm * 64 + mf * 16 + rg * 4 + r;
        const float v = acc[mf][nf][r] + bias;
        if (EPI == 0){
          ((short*)out)[(size_t)row * N + col] = f2bf(v);
        } else if (EPI == 2){
          const float g = 0.5f * v * (1.0f + erff(v * 0.70710678118f));
          ((short*)out)[(size_t)row * N + col] = f2bf(g);
        } else {
          outp[(size_t)row * N + col] = v;
        }
      }
    }
  }
}

// ---------------------------------------------------------------- Attention
// Swapped-operand flash attention + register prefetch + complementary-qb
// makespan balance (R13-verified).
__global__ __launch_bounds__(256) void attn_kernel(
    const short* __restrict__ qkv, short* __restrict__ y)
{
  const int hh = blockIdx.y, b = blockIdx.z;
  const int qb = b ? 15 - blockIdx.x : blockIdx.x;
  const int tid = threadIdx.x, l = tid & 63, w = tid >> 6;
  __shared__ __attribute__((aligned(16))) short vt[2][64 * 72];   // V^T [d][s]
  __shared__ __attribute__((aligned(16))) short pl[4][16 * 72];   // P [q][k]

  const int fr = l & 15;
  const int rg = l >> 4;
  const int fko = rg * 8;
  const float qs = 0.125f * 1.44269504088896f;   // 1/sqrt(64) * log2(e)
  const v4f vz = {0.f, 0.f, 0.f, 0.f};
  const int vd0 = (tid & 7) * 8, vs0 = (tid >> 3) * 2;
  const short* kbase = qkv + (size_t)(b * 1024) * 3072 + 1024 + hh * 64 + fko;

  const size_t qrow = (size_t)(b * 1024 + qb * 64 + w * 16 + fr) * 3072
                      + hh * 64 + fko;
  v8s qf0, qf1;
  {
    const v8s q0 = *(const v8s*)(qkv + qrow);
    const v8s q1 = *(const v8s*)(qkv + qrow + 32);
    #pragma unroll
    for (int j = 0; j < 8; ++j){
      qf0[j] = f2bf(bf2f(q0[j]) * qs);
      qf1[j] = f2bf(bf2f(q1[j]) * qs);
    }
  }

  v4f o[4] = {vz, vz, vz, vz};
  float mrow = -1e30f, lrow = 0.f;

  auto loadK = [&](int kvb, v8s (&kk)[4][2]){
    #pragma unroll
    for (int nf = 0; nf < 4; ++nf){
      const short* kp = kbase + (size_t)(kvb * 64 + nf * 16 + fr) * 3072;
      kk[nf][0] = *(const v8s*)kp;
      kk[nf][1] = *(const v8s*)(kp + 32);
    }
  };
  auto loadV = [&](int kvb, v8s& r0, v8s& r1){
    const short* vsrc = qkv + (size_t)(b * 1024 + kvb * 64 + vs0) * 3072
                        + 2048 + hh * 64 + vd0;
    r0 = *(const v8s*)vsrc;
    r1 = *(const v8s*)(vsrc + 3072);
  };

  v8s kc[4][2], kn[4][2], vc0, vc1, vn0, vn1;
  loadK(0, kc);
  loadV(0, vc0, vc1);

  for (int kvb = 0; kvb <= qb; ++kvb){
    short* vcur = vt[kvb & 1];
    #pragma unroll
    for (int j = 0; j < 8; ++j){
      const uint32_t pk = (uint16_t)vc0[j] | ((uint32_t)(uint16_t)vc1[j] << 16);
      *(uint32_t*)(vcur + (vd0 + j) * 72 + vs0) = pk;
    }
    __syncthreads();
    if (kvb < qb){ loadK(kvb + 1, kn); loadV(kvb + 1, vn0, vn1); }

    v4f s[4] = {vz, vz, vz, vz};
    __builtin_amdgcn_s_setprio(1);
    #pragma unroll
    for (int nf = 0; nf < 4; ++nf){
      s[nf] = __builtin_amdgcn_mfma_f32_16x16x32_bf16(kc[nf][0], qf0, s[nf], 0, 0, 0);
      s[nf] = __builtin_amdgcn_mfma_f32_16x16x32_bf16(kc[nf][1], qf1, s[nf], 0, 0, 0);
    }
    __builtin_amdgcn_s_setprio(0);

    float pmax = s[0][0];
    #pragma unroll
    for (int nf = 0; nf < 4; ++nf)
      #pragma unroll
      for (int r = 0; r < 4; ++r) pmax = fmaxf(pmax, s[nf][r]);
    pmax = fmaxf(pmax, __shfl_xor(pmax, 16));
    pmax = fmaxf(pmax, __shfl_xor(pmax, 32));
    const float mn = fmaxf(mrow, pmax);
    const float fac = exp2f(mrow - mn);
    float rs = 0.f;
    #pragma unroll
    for (int nf = 0; nf < 4; ++nf)
      #pragma unroll
      for (int r = 0; r < 4; ++r){
        s[nf][r] = exp2f(s[nf][r] - mn);
        rs += s[nf][r];
      }
    rs += __shfl_xor(rs, 16);
    rs += __shfl_xor(rs, 32);
    lrow = lrow * fac + rs;
    mrow = mn;
    #pragma unroll
    for (int nf = 0; nf < 4; ++nf)
      #pragma unroll
      for (int r = 0; r < 4; ++r) o[nf][r] *= fac;

    #pragma unroll
    for (int nf = 0; nf < 4; ++nf){
      uint2 pk;
      pk.x = pk2(s[nf][0], s[nf][1]);
      pk.y = pk2(s[nf][2], s[nf][3]);
      *(uint2*)(pl[w] + fr * 72 + nf * 16 + rg * 4) = pk;
    }

    __builtin_amdgcn_s_setprio(1);
    #pragma unroll
    for (int ks = 0; ks < 2; ++ks){
      const v8s pa = *(const v8s*)(pl[w] + fr * 72 + ks * 32 + fko);
      #pragma unroll
      for (int nf = 0; nf < 4; ++nf){
        const v8s vb = *(const v8s*)(vcur + (nf * 16 + fr) * 72 + ks * 32 + fko);
        o[nf] = __builtin_amdgcn_mfma_f32_16x16x32_bf16(vb, pa, o[nf], 0, 0, 0);
      }
    }
    __builtin_amdgcn_s_setprio(0);

    if (kvb < qb){
      #pragma unroll
      for (int nf = 0; nf < 4; ++nf){ kc[nf][0] = kn[nf][0]; kc[nf][1] = kn[nf][1]; }
      vc0 = vn0; vc1 = vn1;
    }
  }

  const float inv = 1.0f / lrow;
  const size_t orow = (size_t)(b * 1024 + qb * 64 + w * 16 + fr) * 1024 + hh * 64;
  #pragma unroll
  for (int nf = 0; nf < 4; ++nf){
    short4 sv;
    sv.x = f2bf(o[nf][0] * inv);
    sv.y = f2bf(o[nf][1] * inv);
    sv.z = f2bf(o[nf][2] * inv);
    sv.w = f2bf(o[nf][3] * inv);
    *(short4*)(y + orow + nf * 16 + rg * 4) = sv;
  }
}

// ---------------------------------------------------------------- launch
extern "C" void kernel_launch(void* const* d_in, const int* in_sizes, int n_in,
                              void* d_out, int out_size, void* d_ws, size_t ws_size,
                              hipStream_t stream)
{
  const float* seq  = (const float*)d_in[0];
  const float* ln1w = (const float*)d_in[1];
  const float* ln1b = (const float*)d_in[2];
  const float* Wq   = (const float*)d_in[3];
  const float* bq   = (const float*)d_in[4];
  const float* Wk   = (const float*)d_in[5];
  const float* bk   = (const float*)d_in[6];
  const float* Wv   = (const float*)d_in[7];
  const float* bv   = (const float*)d_in[8];
  const float* Wp   = (const float*)d_in[9];
  const float* bp   = (const float*)d_in[10];
  const float* ln2w = (const float*)d_in[11];
  const float* ln2b = (const float*)d_in[12];
  const float* W1   = (const float*)d_in[13];
  const float* b1   = (const float*)d_in[14];
  const float* W2   = (const float*)d_in[15];
  const float* b2   = (const float*)d_in[16];
  const float* lnfw = (const float*)d_in[17];
  const float* lnfb = (const float*)d_in[18];

  char* p = (char*)d_ws;
  auto carve = [&](size_t bytes){
    void* r = (void*)p;
    p += (bytes + 255) & ~(size_t)255;
    return r;
  };
  short* wtQKV = (short*)carve((size_t)8 * 3072 * 1024 * 2);
  short* wtP   = (short*)carve((size_t)8 * 1024 * 1024 * 2);
  short* wt1   = (short*)carve((size_t)8 * 4096 * 1024 * 2);
  short* wt2   = (short*)carve((size_t)8 * 1024 * 4096 * 2);
  float* x     = (float*)carve((size_t)2048 * 1024 * 4);
  short* h     = (short*)carve((size_t)2048 * 1024 * 2);
  short* qkv   = (short*)carve((size_t)2048 * 3072 * 2);
  short* y     = (short*)carve((size_t)2048 * 1024 * 2);
  short* hm    = (short*)carve((size_t)2048 * 4096 * 2);
  float* part  = (float*)carve((size_t)4 * 2048 * 1024 * 4);

  const size_t S1M = (size_t)1024 * 1024, S3M = (size_t)3072 * 1024,
               S4M = (size_t)4096 * 1024;

  wconv_all<<<dim3(3072, 8), 256, 0, stream>>>(
      Wq, Wk, Wv, Wp, W1, W2, wtQKV, wtP, wt1, wt2);

  ln_kernel<<<2048, 256, 0, stream>>>(seq, ln1w, ln1b, h);

  for (int l = 0; l < 8; ++l){
    const float* xin = (l == 0) ? seq : x;
    // QKV: 128x128 tiles -> (24,16) = 384 blocks (3/CU capable)
    gemm6<0><<<dim3(24, 16, 1), 256, 0, stream>>>(
        h, wtQKV + l * S3M, qkv, bq + l * 1024, bk + l * 1024, bv + l * 1024,
        2048, 3072, 1024, 1024);
    attn_kernel<<<dim3(16, 16, 2), 256, 0, stream>>>(qkv, y);
    // P projection: split-K2 -> (8,16,2) = 256 blocks
    gemm6<3><<<dim3(8, 16, 2), 256, 0, stream>>>(
        y, wtP + l * S1M, part, nullptr, nullptr, nullptr,
        2048, 1024, 1024, 512);
    reduce_ln<2, false><<<2048, 256, 0, stream>>>(
        part, xin, bp + l * 1024, x, ln2w + l * 1024, ln2b + l * 1024, h);
    // MLP1: (32,16) = 512 blocks
    gemm6<2><<<dim3(32, 16, 1), 256, 0, stream>>>(
        h, wt1 + l * S4M, hm, b1 + l * 4096, nullptr, nullptr,
        2048, 4096, 1024, 1024);
    // MLP2: split-K4 -> (8,16,4) = 512 blocks
    gemm6<3><<<dim3(8, 16, 4), 256, 0, stream>>>(
        hm, wt2 + l * S4M, part, nullptr, nullptr, nullptr,
        2048, 1024, 4096, 1024);
    if (l < 7){
      reduce_ln<4, false><<<2048, 256, 0, stream>>>(
          part, x, b2 + l * 1024, x, ln1w + (l + 1) * 1024,
          ln1b + (l + 1) * 1024, h);
    } else {
      reduce_ln<4, true><<<2048, 256, 0, stream>>>(
          part, x, b2 + l * 1024, x, lnfw, lnfb, d_out);
    }
  }
}

// Round 15
// 1257.071 us; speedup vs baseline: 1.0434x; 1.0434x over previous
//
#include <hip/hip_runtime.h>
#include <cstdint>

#define DEVI __device__ __forceinline__

typedef short v8s __attribute__((ext_vector_type(8)));
typedef float v4f __attribute__((ext_vector_type(4)));

DEVI short f2bf(float f){
  uint32_t u = __builtin_bit_cast(uint32_t, f);
  u += 0x7FFF + ((u >> 16) & 1);          // round-to-nearest-even
  return (short)(u >> 16);
}
DEVI float bf2f(short s){
  uint32_t u = ((uint32_t)(uint16_t)s) << 16;
  return __builtin_bit_cast(float, u);
}
DEVI uint32_t pk2(float a, float b){
  return (uint32_t)(uint16_t)f2bf(a) | ((uint32_t)(uint16_t)f2bf(b) << 16);
}

DEVI void gload16(const void* g, void* l){
  __builtin_amdgcn_global_load_lds(
      (const __attribute__((address_space(1))) unsigned*)g,
      (__attribute__((address_space(3))) unsigned*)l, 16, 0, 0);
}

// ---------------------------------------------------------------- LayerNorm
__global__ __launch_bounds__(256) void ln_kernel(
    const float* __restrict__ x, const float* __restrict__ w,
    const float* __restrict__ b, void* __restrict__ out)
{
  const int row = blockIdx.x;
  const int t = threadIdx.x;
  const float4 v = ((const float4*)(x + (size_t)row * 1024))[t];
  float s  = v.x + v.y + v.z + v.w;
  float s2 = v.x*v.x + v.y*v.y + v.z*v.z + v.w*v.w;
  #pragma unroll
  for (int m = 1; m < 64; m <<= 1){ s += __shfl_xor(s, m); s2 += __shfl_xor(s2, m); }
  __shared__ float ps[4], ps2[4];
  if ((t & 63) == 0){ ps[t >> 6] = s; ps2[t >> 6] = s2; }
  __syncthreads();
  s  = ps[0] + ps[1] + ps[2] + ps[3];
  s2 = ps2[0] + ps2[1] + ps2[2] + ps2[3];
  const float mu = s * (1.f / 1024.f);
  const float rs = rsqrtf(s2 * (1.f / 1024.f) - mu * mu + 1e-5f);
  const float4 wv = ((const float4*)w)[t];
  const float4 bv = ((const float4*)b)[t];
  uint2 pk;
  pk.x = pk2((v.x - mu) * rs * wv.x + bv.x, (v.y - mu) * rs * wv.y + bv.y);
  pk.y = pk2((v.z - mu) * rs * wv.z + bv.z, (v.w - mu) * rs * wv.w + bv.w);
  ((uint2*)out)[(size_t)row * 256 + t] = pk;
}

// ------------- split-K reduce + residual + bias, fused with LayerNorm.
template<int S, bool FIN>
__global__ __launch_bounds__(256) void reduce_ln(
    const float* __restrict__ part, const float* __restrict__ resid,
    const float* __restrict__ bias, float* __restrict__ xout,
    const float* __restrict__ lw, const float* __restrict__ lb,
    void* __restrict__ hout)
{
  const int row = blockIdx.x;
  const int t = threadIdx.x;
  float4 v = ((const float4*)(resid + (size_t)row * 1024))[t];
  const float4 bz = ((const float4*)bias)[t];
  v.x += bz.x; v.y += bz.y; v.z += bz.z; v.w += bz.w;
  #pragma unroll
  for (int s = 0; s < S; ++s){
    const float4 pv = ((const float4*)(part + ((size_t)s * 2048 + row) * 1024))[t];
    v.x += pv.x; v.y += pv.y; v.z += pv.z; v.w += pv.w;
  }
  ((float4*)(xout + (size_t)row * 1024))[t] = v;
  float s  = v.x + v.y + v.z + v.w;
  float s2 = v.x*v.x + v.y*v.y + v.z*v.z + v.w*v.w;
  #pragma unroll
  for (int m = 1; m < 64; m <<= 1){ s += __shfl_xor(s, m); s2 += __shfl_xor(s2, m); }
  __shared__ float ps[4], ps2[4];
  if ((t & 63) == 0){ ps[t >> 6] = s; ps2[t >> 6] = s2; }
  __syncthreads();
  s  = ps[0] + ps[1] + ps[2] + ps[3];
  s2 = ps2[0] + ps2[1] + ps2[2] + ps2[3];
  const float mu = s * (1.f / 1024.f);
  const float rs = rsqrtf(s2 * (1.f / 1024.f) - mu * mu + 1e-5f);
  const float4 wv = ((const float4*)lw)[t];
  const float4 bv = ((const float4*)lb)[t];
  const float o0 = (v.x - mu) * rs * wv.x + bv.x;
  const float o1 = (v.y - mu) * rs * wv.y + bv.y;
  const float o2 = (v.z - mu) * rs * wv.z + bv.z;
  const float o3 = (v.w - mu) * rs * wv.w + bv.w;
  if (FIN){
    ((float4*)hout)[(size_t)row * 256 + t] = make_float4(o0, o1, o2, o3);
  } else {
    uint2 pk;
    pk.x = pk2(o0, o1);
    pk.y = pk2(o2, o3);
    ((uint2*)hout)[(size_t)row * 256 + t] = pk;
  }
}

// ---------------- all weights fp32[K][N] -> bf16[N][K] in ONE dispatch.
// 64n x 256k per block: transpose accumulated in LDS (tb[64][264] bf16), then
// a single write phase of 64 contiguous 512B row segments (4x longer DRAM
// bursts than the old per-chunk 128B scatter). Staging st[64][65] fp32,
// column reads 2-way bank-aliased (free). LDS 49.3KB -> 3 blocks/CU.
// grid = (768, 8): y = layer, x = job id.
__global__ __launch_bounds__(256) void wconv_all(
    const float* __restrict__ Wq, const float* __restrict__ Wk,
    const float* __restrict__ Wv, const float* __restrict__ Wp,
    const float* __restrict__ W1, const float* __restrict__ W2,
    short* __restrict__ wtQKV, short* __restrict__ wtP,
    short* __restrict__ wt1, short* __restrict__ wt2)
{
  const int j = blockIdx.x;
  const size_t l = blockIdx.y;
  const size_t S1M = 1048576, S3M = 3145728, S4M = 4194304;
  const float* W; short* Wt; int K, N, n0, k0;
  if (j < 256){
    const int which = j >> 6, jj = j & 63;      // 16n x 4kc
    n0 = (jj & 15) * 64; k0 = (jj >> 4) * 256; K = 1024; N = 1024;
    if (which == 0){ W = Wq + l * S1M; Wt = wtQKV + l * S3M; }
    else if (which == 1){ W = Wk + l * S1M; Wt = wtQKV + l * S3M + S1M; }
    else if (which == 2){ W = Wv + l * S1M; Wt = wtQKV + l * S3M + 2 * S1M; }
    else { W = Wp + l * S1M; Wt = wtP + l * S1M; }
  } else if (j < 512){
    const int jj = j - 256;                     // 64n x 4kc
    n0 = (jj & 63) * 64; k0 = (jj >> 6) * 256; K = 1024; N = 4096;
    W = W1 + l * S4M; Wt = wt1 + l * S4M;
  } else {
    const int jj = j - 512;                     // 16n x 16kc
    n0 = (jj & 15) * 64; k0 = (jj >> 4) * 256; K = 4096; N = 1024;
    W = W2 + l * S4M; Wt = wt2 + l * S4M;
  }
  __shared__ float st[64][65];
  __shared__ short tb[64 * 264];                // [n][k 256+8 pad]
  const int tid = threadIdx.x;
  const int c4 = (tid & 15) * 4, r = tid >> 4;  // staging coords
  const int nn = tid >> 3, k8 = (tid & 7) * 8;  // transpose coords

  #pragma unroll
  for (int sub = 0; sub < 4; ++sub){
    const int ks = k0 + sub * 64;
    #pragma unroll
    for (int i = 0; i < 4; ++i){
      const float4 v = *(const float4*)(W + (size_t)(ks + r + i*16) * N + n0 + c4);
      st[r + i*16][c4 + 0] = v.x;
      st[r + i*16][c4 + 1] = v.y;
      st[r + i*16][c4 + 2] = v.z;
      st[r + i*16][c4 + 3] = v.w;
    }
    __syncthreads();
    #pragma unroll
    for (int half = 0; half < 2; ++half){
      const int n = nn + half * 32;
      v8s s;
      #pragma unroll
      for (int q = 0; q < 8; ++q) s[q] = f2bf(st[k8 + q][n]);
      *(v8s*)(tb + n * 264 + sub * 64 + k8) = s;
    }
    __syncthreads();
  }
  // write phase: 64 rows x 512B contiguous segments
  #pragma unroll
  for (int p = 0; p < 8; ++p){
    const int flat = tid + p * 256;
    const int n = flat >> 5, kseg = (flat & 31) * 8;
    const v8s s = *(const v8s*)(tb + n * 264 + kseg);
    *(v8s*)(Wt + (size_t)(n0 + n) * K + k0 + kseg) = s;
  }
}

// ---------------------------------------------------------------- GEMM 64x128
// R13-verified operating point: 256 thr = 4 waves (2x2 of 32x64 out),
// SINGLE-buffer 24.6 KB LDS, 4 blocks/CU; loop = sync; stage; sync; compute.
// Latency hiding from co-resident blocks (m114). n-fastest XCD chunks (T1);
// T2 XOR-swizzle. Split-K via z (EPI 3 -> fp32 partials).
template<int EPI>
__global__ __launch_bounds__(256, 4) void gemm5(
    const short* __restrict__ A, const short* __restrict__ Bt,
    void* __restrict__ out,
    const float* __restrict__ b0, const float* __restrict__ b1,
    const float* __restrict__ b2, int M, int N, int K, int kchunk)
{
  __shared__ __attribute__((aligned(16))) short a_t[64 * 64];
  __shared__ __attribute__((aligned(16))) short b_t[128 * 64];
  const int tid = threadIdx.x, l = tid & 63, w = tid >> 6;

  const int gx = gridDim.x;
  const int bid = blockIdx.y * gx + blockIdx.x;
  const int cpx = (gx * gridDim.y) >> 3;
  const int swz = (bid & 7) * cpx + (bid >> 3);
  const int m0 = (swz / gx) * 64, n0 = (swz % gx) * 128;
  const int kt0 = blockIdx.z * kchunk;

  const int lr = l >> 3;                        // staging row within 8-group
  const int scol = ((l & 7) * 16) ^ (lr << 4);  // pre-swizzled source byte col
  const int wm = w >> 1, wn = w & 1;            // wave grid 2x2
  const int fr = l & 15;
  const int rg = l >> 4;
  const int rxor = (fr & 7) << 4;               // read-side XOR (bytes)

  const v4f vz = {0.f, 0.f, 0.f, 0.f};
  v4f acc[2][4];
  #pragma unroll
  for (int i = 0; i < 2; ++i)
    #pragma unroll
    for (int j = 0; j < 4; ++j) acc[i][j] = vz;

  const char* Ab = (const char*)A;
  const char* Bb = (const char*)Bt;
  auto stage = [&](int kt){
    #pragma unroll
    for (int j = 0; j < 2; ++j){                // A: 16 rows per wave
      const int rb = w * 16 + j * 8;
      gload16(Ab + ((size_t)(m0 + rb + lr) * K + kt) * 2 + scol,
              (char*)a_t + rb * 128);
    }
    #pragma unroll
    for (int j = 0; j < 4; ++j){                // B: 32 rows per wave
      const int rb = w * 32 + j * 8;
      gload16(Bb + ((size_t)(n0 + rb + lr) * K + kt) * 2 + scol,
              (char*)b_t + rb * 128);
    }
  };

  const int NT = kchunk >> 6;
  for (int t = 0; t < NT; ++t){
    __syncthreads();                  // prior step's LDS reads complete
    stage(kt0 + (t << 6));
    __syncthreads();                  // implicit vmcnt(0): tile resident
    __builtin_amdgcn_s_setprio(1);
    #pragma unroll
    for (int ks = 0; ks < 2; ++ks){
      const int co = ks * 64 + rg * 16;
      v8s af[2], bf[4];
      #pragma unroll
      for (int mf = 0; mf < 2; ++mf)
        af[mf] = *(const v8s*)((char*)a_t + (wm * 32 + mf * 16 + fr) * 128
                               + (co ^ rxor));
      #pragma unroll
      for (int nf = 0; nf < 4; ++nf)
        bf[nf] = *(const v8s*)((char*)b_t + (wn * 64 + nf * 16 + fr) * 128
                               + (co ^ rxor));
      #pragma unroll
      for (int mf = 0; mf < 2; ++mf)
        #pragma unroll
        for (int nf = 0; nf < 4; ++nf)
          acc[mf][nf] = __builtin_amdgcn_mfma_f32_16x16x32_bf16(
              af[mf], bf[nf], acc[mf][nf], 0, 0, 0);
    }
    __builtin_amdgcn_s_setprio(0);
  }

  float* outp = (EPI == 3)
      ? (float*)out + (size_t)blockIdx.z * ((size_t)M * N) : (float*)out;
  #pragma unroll
  for (int mf = 0; mf < 2; ++mf){
    #pragma unroll
    for (int nf = 0; nf < 4; ++nf){
      const int col = n0 + wn * 64 + nf * 16 + fr;
      float bias = 0.f;
      if (EPI == 0)
        bias = col < 1024 ? b0[col] : (col < 2048 ? b1[col - 1024] : b2[col - 2048]);
      else if (EPI == 2)
        bias = b0[col];
      #pragma unroll
      for (int r = 0; r < 4; ++r){
        const int row = m0 + wm * 32 + mf * 16 + rg * 4 + r;
        const float v = acc[mf][nf][r] + bias;
        if (EPI == 0){
          ((short*)out)[(size_t)row * N + col] = f2bf(v);
        } else if (EPI == 2){
          const float g = 0.5f * v * (1.0f + erff(v * 0.70710678118f));
          ((short*)out)[(size_t)row * N + col] = f2bf(g);
        } else {
          outp[(size_t)row * N + col] = v;
        }
      }
    }
  }
}

// ---------------------------------------------------------------- Attention
// Swapped-operand flash attention + register prefetch + complementary-qb
// makespan balance (R13-verified).
__global__ __launch_bounds__(256) void attn_kernel(
    const short* __restrict__ qkv, short* __restrict__ y)
{
  const int hh = blockIdx.y, b = blockIdx.z;
  const int qb = b ? 15 - blockIdx.x : blockIdx.x;
  const int tid = threadIdx.x, l = tid & 63, w = tid >> 6;
  __shared__ __attribute__((aligned(16))) short vt[2][64 * 72];   // V^T [d][s]
  __shared__ __attribute__((aligned(16))) short pl[4][16 * 72];   // P [q][k]

  const int fr = l & 15;
  const int rg = l >> 4;
  const int fko = rg * 8;
  const float qs = 0.125f * 1.44269504088896f;   // 1/sqrt(64) * log2(e)
  const v4f vz = {0.f, 0.f, 0.f, 0.f};
  const int vd0 = (tid & 7) * 8, vs0 = (tid >> 3) * 2;
  const short* kbase = qkv + (size_t)(b * 1024) * 3072 + 1024 + hh * 64 + fko;

  const size_t qrow = (size_t)(b * 1024 + qb * 64 + w * 16 + fr) * 3072
                      + hh * 64 + fko;
  v8s qf0, qf1;
  {
    const v8s q0 = *(const v8s*)(qkv + qrow);
    const v8s q1 = *(const v8s*)(qkv + qrow + 32);
    #pragma unroll
    for (int j = 0; j < 8; ++j){
      qf0[j] = f2bf(bf2f(q0[j]) * qs);
      qf1[j] = f2bf(bf2f(q1[j]) * qs);
    }
  }

  v4f o[4] = {vz, vz, vz, vz};
  float mrow = -1e30f, lrow = 0.f;

  auto loadK = [&](int kvb, v8s (&kk)[4][2]){
    #pragma unroll
    for (int nf = 0; nf < 4; ++nf){
      const short* kp = kbase + (size_t)(kvb * 64 + nf * 16 + fr) * 3072;
      kk[nf][0] = *(const v8s*)kp;
      kk[nf][1] = *(const v8s*)(kp + 32);
    }
  };
  auto loadV = [&](int kvb, v8s& r0, v8s& r1){
    const short* vsrc = qkv + (size_t)(b * 1024 + kvb * 64 + vs0) * 3072
                        + 2048 + hh * 64 + vd0;
    r0 = *(const v8s*)vsrc;
    r1 = *(const v8s*)(vsrc + 3072);
  };

  v8s kc[4][2], kn[4][2], vc0, vc1, vn0, vn1;
  loadK(0, kc);
  loadV(0, vc0, vc1);

  for (int kvb = 0; kvb <= qb; ++kvb){
    short* vcur = vt[kvb & 1];
    #pragma unroll
    for (int j = 0; j < 8; ++j){
      const uint32_t pk = (uint16_t)vc0[j] | ((uint32_t)(uint16_t)vc1[j] << 16);
      *(uint32_t*)(vcur + (vd0 + j) * 72 + vs0) = pk;
    }
    __syncthreads();
    if (kvb < qb){ loadK(kvb + 1, kn); loadV(kvb + 1, vn0, vn1); }

    v4f s[4] = {vz, vz, vz, vz};
    __builtin_amdgcn_s_setprio(1);
    #pragma unroll
    for (int nf = 0; nf < 4; ++nf){
      s[nf] = __builtin_amdgcn_mfma_f32_16x16x32_bf16(kc[nf][0], qf0, s[nf], 0, 0, 0);
      s[nf] = __builtin_amdgcn_mfma_f32_16x16x32_bf16(kc[nf][1], qf1, s[nf], 0, 0, 0);
    }
    __builtin_amdgcn_s_setprio(0);

    float pmax = s[0][0];
    #pragma unroll
    for (int nf = 0; nf < 4; ++nf)
      #pragma unroll
      for (int r = 0; r < 4; ++r) pmax = fmaxf(pmax, s[nf][r]);
    pmax = fmaxf(pmax, __shfl_xor(pmax, 16));
    pmax = fmaxf(pmax, __shfl_xor(pmax, 32));
    const float mn = fmaxf(mrow, pmax);
    const float fac = exp2f(mrow - mn);
    float rs = 0.f;
    #pragma unroll
    for (int nf = 0; nf < 4; ++nf)
      #pragma unroll
      for (int r = 0; r < 4; ++r){
        s[nf][r] = exp2f(s[nf][r] - mn);
        rs += s[nf][r];
      }
    rs += __shfl_xor(rs, 16);
    rs += __shfl_xor(rs, 32);
    lrow = lrow * fac + rs;
    mrow = mn;
    #pragma unroll
    for (int nf = 0; nf < 4; ++nf)
      #pragma unroll
      for (int r = 0; r < 4; ++r) o[nf][r] *= fac;

    #pragma unroll
    for (int nf = 0; nf < 4; ++nf){
      uint2 pk;
      pk.x = pk2(s[nf][0], s[nf][1]);
      pk.y = pk2(s[nf][2], s[nf][3]);
      *(uint2*)(pl[w] + fr * 72 + nf * 16 + rg * 4) = pk;
    }

    __builtin_amdgcn_s_setprio(1);
    #pragma unroll
    for (int ks = 0; ks < 2; ++ks){
      const v8s pa = *(const v8s*)(pl[w] + fr * 72 + ks * 32 + fko);
      #pragma unroll
      for (int nf = 0; nf < 4; ++nf){
        const v8s vb = *(const v8s*)(vcur + (nf * 16 + fr) * 72 + ks * 32 + fko);
        o[nf] = __builtin_amdgcn_mfma_f32_16x16x32_bf16(vb, pa, o[nf], 0, 0, 0);
      }
    }
    __builtin_amdgcn_s_setprio(0);

    if (kvb < qb){
      #pragma unroll
      for (int nf = 0; nf < 4; ++nf){ kc[nf][0] = kn[nf][0]; kc[nf][1] = kn[nf][1]; }
      vc0 = vn0; vc1 = vn1;
    }
  }

  const float inv = 1.0f / lrow;
  const size_t orow = (size_t)(b * 1024 + qb * 64 + w * 16 + fr) * 1024 + hh * 64;
  #pragma unroll
  for (int nf = 0; nf < 4; ++nf){
    short4 sv;
    sv.x = f2bf(o[nf][0] * inv);
    sv.y = f2bf(o[nf][1] * inv);
    sv.z = f2bf(o[nf][2] * inv);
    sv.w = f2bf(o[nf][3] * inv);
    *(short4*)(y + orow + nf * 16 + rg * 4) = sv;
  }
}

// ---------------------------------------------------------------- launch
extern "C" void kernel_launch(void* const* d_in, const int* in_sizes, int n_in,
                              void* d_out, int out_size, void* d_ws, size_t ws_size,
                              hipStream_t stream)
{
  const float* seq  = (const float*)d_in[0];
  const float* ln1w = (const float*)d_in[1];
  const float* ln1b = (const float*)d_in[2];
  const float* Wq   = (const float*)d_in[3];
  const float* bq   = (const float*)d_in[4];
  const float* Wk   = (const float*)d_in[5];
  const float* bk   = (const float*)d_in[6];
  const float* Wv   = (const float*)d_in[7];
  const float* bv   = (const float*)d_in[8];
  const float* Wp   = (const float*)d_in[9];
  const float* bp   = (const float*)d_in[10];
  const float* ln2w = (const float*)d_in[11];
  const float* ln2b = (const float*)d_in[12];
  const float* W1   = (const float*)d_in[13];
  const float* b1   = (const float*)d_in[14];
  const float* W2   = (const float*)d_in[15];
  const float* b2   = (const float*)d_in[16];
  const float* lnfw = (const float*)d_in[17];
  const float* lnfb = (const float*)d_in[18];

  char* p = (char*)d_ws;
  auto carve = [&](size_t bytes){
    void* r = (void*)p;
    p += (bytes + 255) & ~(size_t)255;
    return r;
  };
  short* wtQKV = (short*)carve((size_t)8 * 3072 * 1024 * 2);
  short* wtP   = (short*)carve((size_t)8 * 1024 * 1024 * 2);
  short* wt1   = (short*)carve((size_t)8 * 4096 * 1024 * 2);
  short* wt2   = (short*)carve((size_t)8 * 1024 * 4096 * 2);
  float* x     = (float*)carve((size_t)2048 * 1024 * 4);
  short* h     = (short*)carve((size_t)2048 * 1024 * 2);
  short* qkv   = (short*)carve((size_t)2048 * 3072 * 2);
  short* y     = (short*)carve((size_t)2048 * 1024 * 2);
  short* hm    = (short*)carve((size_t)2048 * 4096 * 2);
  float* part  = (float*)carve((size_t)4 * 2048 * 1024 * 4);

  const size_t S1M = (size_t)1024 * 1024, S3M = (size_t)3072 * 1024,
               S4M = (size_t)4096 * 1024;

  wconv_all<<<dim3(768, 8), 256, 0, stream>>>(
      Wq, Wk, Wv, Wp, W1, W2, wtQKV, wtP, wt1, wt2);

  ln_kernel<<<2048, 256, 0, stream>>>(seq, ln1w, ln1b, h);

  for (int l = 0; l < 8; ++l){
    const float* xin = (l == 0) ? seq : x;
    // QKV: (24,32) = 768 blocks
    gemm5<0><<<dim3(24, 32, 1), 256, 0, stream>>>(
        h, wtQKV + l * S3M, qkv, bq + l * 1024, bk + l * 1024, bv + l * 1024,
        2048, 3072, 1024, 1024);
    attn_kernel<<<dim3(16, 16, 2), 256, 0, stream>>>(qkv, y);
    // P projection: split-K2 -> (8,32,2) = 512 blocks
    gemm5<3><<<dim3(8, 32, 2), 256, 0, stream>>>(
        y, wtP + l * S1M, part, nullptr, nullptr, nullptr,
        2048, 1024, 1024, 512);
    reduce_ln<2, false><<<2048, 256, 0, stream>>>(
        part, xin, bp + l * 1024, x, ln2w + l * 1024, ln2b + l * 1024, h);
    // MLP1: (32,32) = 1024 blocks
    gemm5<2><<<dim3(32, 32, 1), 256, 0, stream>>>(
        h, wt1 + l * S4M, hm, b1 + l * 4096, nullptr, nullptr,
        2048, 4096, 1024, 1024);
    // MLP2: split-K4 -> (8,32,4) = 1024 blocks
    gemm5<3><<<dim3(8, 32, 4), 256, 0, stream>>>(
        hm, wt2 + l * S4M, part, nullptr, nullptr, nullptr,
        2048, 1024, 4096, 1024);
    if (l < 7){
      reduce_ln<4, false><<<2048, 256, 0, stream>>>(
          part, x, b2 + l * 1024, x, ln1w + (l + 1) * 1024,
          ln1b + (l + 1) * 1024, h);
    } else {
      reduce_ln<4, true><<<2048, 256, 0, stream>>>(
          part, x, b2 + l * 1024, x, lnfw, lnfb, d_out);
    }
  }
}

// Round 17
// 1249.671 us; speedup vs baseline: 1.0496x; 1.0059x over previous
//
#include <hip/hip_runtime.h>
#include <cstdint>

#define DEVI __device__ __forceinline__

typedef short v8s __attribute__((ext_vector_type(8)));
typedef float v4f __attribute__((ext_vector_type(4)));

DEVI short f2bf(float f){
  uint32_t u = __builtin_bit_cast(uint32_t, f);
  u += 0x7FFF + ((u >> 16) & 1);          // round-to-nearest-even
  return (short)(u >> 16);
}
DEVI float bf2f(short s){
  uint32_t u = ((uint32_t)(uint16_t)s) << 16;
  return __builtin_bit_cast(float, u);
}
DEVI uint32_t pk2(float a, float b){
  return (uint32_t)(uint16_t)f2bf(a) | ((uint32_t)(uint16_t)f2bf(b) << 16);
}

DEVI void gload16(const void* g, void* l){
  __builtin_amdgcn_global_load_lds(
      (const __attribute__((address_space(1))) unsigned*)g,
      (__attribute__((address_space(3))) unsigned*)l, 16, 0, 0);
}

// ---------------------------------------------------------------- LayerNorm
__global__ __launch_bounds__(256) void ln_kernel(
    const float* __restrict__ x, const float* __restrict__ w,
    const float* __restrict__ b, void* __restrict__ out)
{
  const int row = blockIdx.x;
  const int t = threadIdx.x;
  const float4 v = ((const float4*)(x + (size_t)row * 1024))[t];
  float s  = v.x + v.y + v.z + v.w;
  float s2 = v.x*v.x + v.y*v.y + v.z*v.z + v.w*v.w;
  #pragma unroll
  for (int m = 1; m < 64; m <<= 1){ s += __shfl_xor(s, m); s2 += __shfl_xor(s2, m); }
  __shared__ float ps[4], ps2[4];
  if ((t & 63) == 0){ ps[t >> 6] = s; ps2[t >> 6] = s2; }
  __syncthreads();
  s  = ps[0] + ps[1] + ps[2] + ps[3];
  s2 = ps2[0] + ps2[1] + ps2[2] + ps2[3];
  const float mu = s * (1.f / 1024.f);
  const float rs = rsqrtf(s2 * (1.f / 1024.f) - mu * mu + 1e-5f);
  const float4 wv = ((const float4*)w)[t];
  const float4 bv = ((const float4*)b)[t];
  uint2 pk;
  pk.x = pk2((v.x - mu) * rs * wv.x + bv.x, (v.y - mu) * rs * wv.y + bv.y);
  pk.y = pk2((v.z - mu) * rs * wv.z + bv.z, (v.w - mu) * rs * wv.w + bv.w);
  ((uint2*)out)[(size_t)row * 256 + t] = pk;
}

// ------------- split-K reduce + residual + bias, fused with LayerNorm.
template<int S, bool FIN>
__global__ __launch_bounds__(256) void reduce_ln(
    const float* __restrict__ part, const float* __restrict__ resid,
    const float* __restrict__ bias, float* __restrict__ xout,
    const float* __restrict__ lw, const float* __restrict__ lb,
    void* __restrict__ hout)
{
  const int row = blockIdx.x;
  const int t = threadIdx.x;
  float4 v = ((const float4*)(resid + (size_t)row * 1024))[t];
  const float4 bz = ((const float4*)bias)[t];
  v.x += bz.x; v.y += bz.y; v.z += bz.z; v.w += bz.w;
  #pragma unroll
  for (int s = 0; s < S; ++s){
    const float4 pv = ((const float4*)(part + ((size_t)s * 2048 + row) * 1024))[t];
    v.x += pv.x; v.y += pv.y; v.z += pv.z; v.w += pv.w;
  }
  ((float4*)(xout + (size_t)row * 1024))[t] = v;
  float s  = v.x + v.y + v.z + v.w;
  float s2 = v.x*v.x + v.y*v.y + v.z*v.z + v.w*v.w;
  #pragma unroll
  for (int m = 1; m < 64; m <<= 1){ s += __shfl_xor(s, m); s2 += __shfl_xor(s2, m); }
  __shared__ float ps[4], ps2[4];
  if ((t & 63) == 0){ ps[t >> 6] = s; ps2[t >> 6] = s2; }
  __syncthreads();
  s  = ps[0] + ps[1] + ps[2] + ps[3];
  s2 = ps2[0] + ps2[1] + ps2[2] + ps2[3];
  const float mu = s * (1.f / 1024.f);
  const float rs = rsqrtf(s2 * (1.f / 1024.f) - mu * mu + 1e-5f);
  const float4 wv = ((const float4*)lw)[t];
  const float4 bv = ((const float4*)lb)[t];
  const float o0 = (v.x - mu) * rs * wv.x + bv.x;
  const float o1 = (v.y - mu) * rs * wv.y + bv.y;
  const float o2 = (v.z - mu) * rs * wv.z + bv.z;
  const float o3 = (v.w - mu) * rs * wv.w + bv.w;
  if (FIN){
    ((float4*)hout)[(size_t)row * 256 + t] = make_float4(o0, o1, o2, o3);
  } else {
    uint2 pk;
    pk.x = pk2(o0, o1);
    pk.y = pk2(o2, o3);
    ((uint2*)hout)[(size_t)row * 256 + t] = pk;
  }
}

// ---------------- all weights fp32[K][N] -> bf16[N][K] in ONE dispatch.
// R15 tiling (64n x 256k, LDS transpose, 512B write segments) + NON-TEMPORAL
// loads/stores (via clang ext_vector types; HIP float4 is rejected by the
// builtin): weights are read once and outputs consumed much later, so L2
// line allocation is pure pollution on both streams.
__global__ __launch_bounds__(256) void wconv_all(
    const float* __restrict__ Wq, const float* __restrict__ Wk,
    const float* __restrict__ Wv, const float* __restrict__ Wp,
    const float* __restrict__ W1, const float* __restrict__ W2,
    short* __restrict__ wtQKV, short* __restrict__ wtP,
    short* __restrict__ wt1, short* __restrict__ wt2)
{
  const int j = blockIdx.x;
  const size_t l = blockIdx.y;
  const size_t S1M = 1048576, S3M = 3145728, S4M = 4194304;
  const float* W; short* Wt; int K, N, n0, k0;
  if (j < 256){
    const int which = j >> 6, jj = j & 63;      // 16n x 4kc
    n0 = (jj & 15) * 64; k0 = (jj >> 4) * 256; K = 1024; N = 1024;
    if (which == 0){ W = Wq + l * S1M; Wt = wtQKV + l * S3M; }
    else if (which == 1){ W = Wk + l * S1M; Wt = wtQKV + l * S3M + S1M; }
    else if (which == 2){ W = Wv + l * S1M; Wt = wtQKV + l * S3M + 2 * S1M; }
    else { W = Wp + l * S1M; Wt = wtP + l * S1M; }
  } else if (j < 512){
    const int jj = j - 256;                     // 64n x 4kc
    n0 = (jj & 63) * 64; k0 = (jj >> 6) * 256; K = 1024; N = 4096;
    W = W1 + l * S4M; Wt = wt1 + l * S4M;
  } else {
    const int jj = j - 512;                     // 16n x 16kc
    n0 = (jj & 15) * 64; k0 = (jj >> 4) * 256; K = 4096; N = 1024;
    W = W2 + l * S4M; Wt = wt2 + l * S4M;
  }
  __shared__ float st[64][65];
  __shared__ short tb[64 * 264];                // [n][k 256+8 pad]
  const int tid = threadIdx.x;
  const int c4 = (tid & 15) * 4, r = tid >> 4;  // staging coords
  const int nn = tid >> 3, k8 = (tid & 7) * 8;  // transpose coords

  #pragma unroll
  for (int sub = 0; sub < 4; ++sub){
    const int ks = k0 + sub * 64;
    #pragma unroll
    for (int i = 0; i < 4; ++i){
      const v4f v = __builtin_nontemporal_load(
          (const v4f*)(W + (size_t)(ks + r + i*16) * N + n0 + c4));
      st[r + i*16][c4 + 0] = v[0];
      st[r + i*16][c4 + 1] = v[1];
      st[r + i*16][c4 + 2] = v[2];
      st[r + i*16][c4 + 3] = v[3];
    }
    __syncthreads();
    #pragma unroll
    for (int half = 0; half < 2; ++half){
      const int n = nn + half * 32;
      v8s s;
      #pragma unroll
      for (int q = 0; q < 8; ++q) s[q] = f2bf(st[k8 + q][n]);
      *(v8s*)(tb + n * 264 + sub * 64 + k8) = s;
    }
    __syncthreads();
  }
  // write phase: 64 rows x 512B contiguous segments, non-temporal
  #pragma unroll
  for (int p = 0; p < 8; ++p){
    const int flat = tid + p * 256;
    const int n = flat >> 5, kseg = (flat & 31) * 8;
    const v8s s = *(const v8s*)(tb + n * 264 + kseg);
    __builtin_nontemporal_store(s, (v8s*)(Wt + (size_t)(n0 + n) * K + k0 + kseg));
  }
}

// ---------------------------------------------------------------- GEMM 64x128
// R13-verified operating point (FROZEN): 256 thr = 4 waves (2x2 of 32x64 out),
// SINGLE-buffer 24.6 KB LDS, 4 blocks/CU; loop = sync; stage; sync; compute.
// Latency hiding from co-resident blocks (m114). n-fastest XCD chunks (T1);
// T2 XOR-swizzle. Split-K via z (EPI 3 -> fp32 partials).
template<int EPI>
__global__ __launch_bounds__(256, 4) void gemm5(
    const short* __restrict__ A, const short* __restrict__ Bt,
    void* __restrict__ out,
    const float* __restrict__ b0, const float* __restrict__ b1,
    const float* __restrict__ b2, int M, int N, int K, int kchunk)
{
  __shared__ __attribute__((aligned(16))) short a_t[64 * 64];
  __shared__ __attribute__((aligned(16))) short b_t[128 * 64];
  const int tid = threadIdx.x, l = tid & 63, w = tid >> 6;

  const int gx = gridDim.x;
  const int bid = blockIdx.y * gx + blockIdx.x;
  const int cpx = (gx * gridDim.y) >> 3;
  const int swz = (bid & 7) * cpx + (bid >> 3);
  const int m0 = (swz / gx) * 64, n0 = (swz % gx) * 128;
  const int kt0 = blockIdx.z * kchunk;

  const int lr = l >> 3;                        // staging row within 8-group
  const int scol = ((l & 7) * 16) ^ (lr << 4);  // pre-swizzled source byte col
  const int wm = w >> 1, wn = w & 1;            // wave grid 2x2
  const int fr = l & 15;
  const int rg = l >> 4;
  const int rxor = (fr & 7) << 4;               // read-side XOR (bytes)

  const v4f vz = {0.f, 0.f, 0.f, 0.f};
  v4f acc[2][4];
  #pragma unroll
  for (int i = 0; i < 2; ++i)
    #pragma unroll
    for (int j = 0; j < 4; ++j) acc[i][j] = vz;

  const char* Ab = (const char*)A;
  const char* Bb = (const char*)Bt;
  auto stage = [&](int kt){
    #pragma unroll
    for (int j = 0; j < 2; ++j){                // A: 16 rows per wave
      const int rb = w * 16 + j * 8;
      gload16(Ab + ((size_t)(m0 + rb + lr) * K + kt) * 2 + scol,
              (char*)a_t + rb * 128);
    }
    #pragma unroll
    for (int j = 0; j < 4; ++j){                // B: 32 rows per wave
      const int rb = w * 32 + j * 8;
      gload16(Bb + ((size_t)(n0 + rb + lr) * K + kt) * 2 + scol,
              (char*)b_t + rb * 128);
    }
  };

  const int NT = kchunk >> 6;
  for (int t = 0; t < NT; ++t){
    __syncthreads();                  // prior step's LDS reads complete
    stage(kt0 + (t << 6));
    __syncthreads();                  // implicit vmcnt(0): tile resident
    __builtin_amdgcn_s_setprio(1);
    #pragma unroll
    for (int ks = 0; ks < 2; ++ks){
      const int co = ks * 64 + rg * 16;
      v8s af[2], bf[4];
      #pragma unroll
      for (int mf = 0; mf < 2; ++mf)
        af[mf] = *(const v8s*)((char*)a_t + (wm * 32 + mf * 16 + fr) * 128
                               + (co ^ rxor));
      #pragma unroll
      for (int nf = 0; nf < 4; ++nf)
        bf[nf] = *(const v8s*)((char*)b_t + (wn * 64 + nf * 16 + fr) * 128
                               + (co ^ rxor));
      #pragma unroll
      for (int mf = 0; mf < 2; ++mf)
        #pragma unroll
        for (int nf = 0; nf < 4; ++nf)
          acc[mf][nf] = __builtin_amdgcn_mfma_f32_16x16x32_bf16(
              af[mf], bf[nf], acc[mf][nf], 0, 0, 0);
    }
    __builtin_amdgcn_s_setprio(0);
  }

  float* outp = (EPI == 3)
      ? (float*)out + (size_t)blockIdx.z * ((size_t)M * N) : (float*)out;
  #pragma unroll
  for (int mf = 0; mf < 2; ++mf){
    #pragma unroll
    for (int nf = 0; nf < 4; ++nf){
      const int col = n0 + wn * 64 + nf * 16 + fr;
      float bias = 0.f;
      if (EPI == 0)
        bias = col < 1024 ? b0[col] : (col < 2048 ? b1[col - 1024] : b2[col - 2048]);
      else if (EPI == 2)
        bias = b0[col];
      #pragma unroll
      for (int r = 0; r < 4; ++r){
        const int row = m0 + wm * 32 + mf * 16 + rg * 4 + r;
        const float v = acc[mf][nf][r] + bias;
        if (EPI == 0){
          ((short*)out)[(size_t)row * N + col] = f2bf(v);
        } else if (EPI == 2){
          const float g = 0.5f * v * (1.0f + erff(v * 0.70710678118f));
          ((short*)out)[(size_t)row * N + col] = f2bf(g);
        } else {
          outp[(size_t)row * N + col] = v;
        }
      }
    }
  }
}

// ---------------------------------------------------------------- Attention
// Swapped-operand flash attention + register prefetch + complementary-qb
// makespan balance (R13-verified, FROZEN).
__global__ __launch_bounds__(256) void attn_kernel(
    const short* __restrict__ qkv, short* __restrict__ y)
{
  const int hh = blockIdx.y, b = blockIdx.z;
  const int qb = b ? 15 - blockIdx.x : blockIdx.x;
  const int tid = threadIdx.x, l = tid & 63, w = tid >> 6;
  __shared__ __attribute__((aligned(16))) short vt[2][64 * 72];   // V^T [d][s]
  __shared__ __attribute__((aligned(16))) short pl[4][16 * 72];   // P [q][k]

  const int fr = l & 15;
  const int rg = l >> 4;
  const int fko = rg * 8;
  const float qs = 0.125f * 1.44269504088896f;   // 1/sqrt(64) * log2(e)
  const v4f vz = {0.f, 0.f, 0.f, 0.f};
  const int vd0 = (tid & 7) * 8, vs0 = (tid >> 3) * 2;
  const short* kbase = qkv + (size_t)(b * 1024) * 3072 + 1024 + hh * 64 + fko;

  const size_t qrow = (size_t)(b * 1024 + qb * 64 + w * 16 + fr) * 3072
                      + hh * 64 + fko;
  v8s qf0, qf1;
  {
    const v8s q0 = *(const v8s*)(qkv + qrow);
    const v8s q1 = *(const v8s*)(qkv + qrow + 32);
    #pragma unroll
    for (int j = 0; j < 8; ++j){
      qf0[j] = f2bf(bf2f(q0[j]) * qs);
      qf1[j] = f2bf(bf2f(q1[j]) * qs);
    }
  }

  v4f o[4] = {vz, vz, vz, vz};
  float mrow = -1e30f, lrow = 0.f;

  auto loadK = [&](int kvb, v8s (&kk)[4][2]){
    #pragma unroll
    for (int nf = 0; nf < 4; ++nf){
      const short* kp = kbase + (size_t)(kvb * 64 + nf * 16 + fr) * 3072;
      kk[nf][0] = *(const v8s*)kp;
      kk[nf][1] = *(const v8s*)(kp + 32);
    }
  };
  auto loadV = [&](int kvb, v8s& r0, v8s& r1){
    const short* vsrc = qkv + (size_t)(b * 1024 + kvb * 64 + vs0) * 3072
                        + 2048 + hh * 64 + vd0;
    r0 = *(const v8s*)vsrc;
    r1 = *(const v8s*)(vsrc + 3072);
  };

  v8s kc[4][2], kn[4][2], vc0, vc1, vn0, vn1;
  loadK(0, kc);
  loadV(0, vc0, vc1);

  for (int kvb = 0; kvb <= qb; ++kvb){
    short* vcur = vt[kvb & 1];
    #pragma unroll
    for (int j = 0; j < 8; ++j){
      const uint32_t pk = (uint16_t)vc0[j] | ((uint32_t)(uint16_t)vc1[j] << 16);
      *(uint32_t*)(vcur + (vd0 + j) * 72 + vs0) = pk;
    }
    __syncthreads();
    if (kvb < qb){ loadK(kvb + 1, kn); loadV(kvb + 1, vn0, vn1); }

    v4f s[4] = {vz, vz, vz, vz};
    __builtin_amdgcn_s_setprio(1);
    #pragma unroll
    for (int nf = 0; nf < 4; ++nf){
      s[nf] = __builtin_amdgcn_mfma_f32_16x16x32_bf16(kc[nf][0], qf0, s[nf], 0, 0, 0);
      s[nf] = __builtin_amdgcn_mfma_f32_16x16x32_bf16(kc[nf][1], qf1, s[nf], 0, 0, 0);
    }
    __builtin_amdgcn_s_setprio(0);

    float pmax = s[0][0];
    #pragma unroll
    for (int nf = 0; nf < 4; ++nf)
      #pragma unroll
      for (int r = 0; r < 4; ++r) pmax = fmaxf(pmax, s[nf][r]);
    pmax = fmaxf(pmax, __shfl_xor(pmax, 16));
    pmax = fmaxf(pmax, __shfl_xor(pmax, 32));
    const float mn = fmaxf(mrow, pmax);
    const float fac = exp2f(mrow - mn);
    float rs = 0.f;
    #pragma unroll
    for (int nf = 0; nf < 4; ++nf)
      #pragma unroll
      for (int r = 0; r < 4; ++r){
        s[nf][r] = exp2f(s[nf][r] - mn);
        rs += s[nf][r];
      }
    rs += __shfl_xor(rs, 16);
    rs += __shfl_xor(rs, 32);
    lrow = lrow * fac + rs;
    mrow = mn;
    #pragma unroll
    for (int nf = 0; nf < 4; ++nf)
      #pragma unroll
      for (int r = 0; r < 4; ++r) o[nf][r] *= fac;

    #pragma unroll
    for (int nf = 0; nf < 4; ++nf){
      uint2 pk;
      pk.x = pk2(s[nf][0], s[nf][1]);
      pk.y = pk2(s[nf][2], s[nf][3]);
      *(uint2*)(pl[w] + fr * 72 + nf * 16 + rg * 4) = pk;
    }

    __builtin_amdgcn_s_setprio(1);
    #pragma unroll
    for (int ks = 0; ks < 2; ++ks){
      const v8s pa = *(const v8s*)(pl[w] + fr * 72 + ks * 32 + fko);
      #pragma unroll
      for (int nf = 0; nf < 4; ++nf){
        const v8s vb = *(const v8s*)(vcur + (nf * 16 + fr) * 72 + ks * 32 + fko);
        o[nf] = __builtin_amdgcn_mfma_f32_16x16x32_bf16(vb, pa, o[nf], 0, 0, 0);
      }
    }
    __builtin_amdgcn_s_setprio(0);

    if (kvb < qb){
      #pragma unroll
      for (int nf = 0; nf < 4; ++nf){ kc[nf][0] = kn[nf][0]; kc[nf][1] = kn[nf][1]; }
      vc0 = vn0; vc1 = vn1;
    }
  }

  const float inv = 1.0f / lrow;
  const size_t orow = (size_t)(b * 1024 + qb * 64 + w * 16 + fr) * 1024 + hh * 64;
  #pragma unroll
  for (int nf = 0; nf < 4; ++nf){
    short4 sv;
    sv.x = f2bf(o[nf][0] * inv);
    sv.y = f2bf(o[nf][1] * inv);
    sv.z = f2bf(o[nf][2] * inv);
    sv.w = f2bf(o[nf][3] * inv);
    *(short4*)(y + orow + nf * 16 + rg * 4) = sv;
  }
}

// ---------------------------------------------------------------- launch
extern "C" void kernel_launch(void* const* d_in, const int* in_sizes, int n_in,
                              void* d_out, int out_size, void* d_ws, size_t ws_size,
                              hipStream_t stream)
{
  const float* seq  = (const float*)d_in[0];
  const float* ln1w = (const float*)d_in[1];
  const float* ln1b = (const float*)d_in[2];
  const float* Wq   = (const float*)d_in[3];
  const float* bq   = (const float*)d_in[4];
  const float* Wk   = (const float*)d_in[5];
  const float* bk   = (const float*)d_in[6];
  const float* Wv   = (const float*)d_in[7];
  const float* bv   = (const float*)d_in[8];
  const float* Wp   = (const float*)d_in[9];
  const float* bp   = (const float*)d_in[10];
  const float* ln2w = (const float*)d_in[11];
  const float* ln2b = (const float*)d_in[12];
  const float* W1   = (const float*)d_in[13];
  const float* b1   = (const float*)d_in[14];
  const float* W2   = (const float*)d_in[15];
  const float* b2   = (const float*)d_in[16];
  const float* lnfw = (const float*)d_in[17];
  const float* lnfb = (const float*)d_in[18];

  char* p = (char*)d_ws;
  auto carve = [&](size_t bytes){
    void* r = (void*)p;
    p += (bytes + 255) & ~(size_t)255;
    return r;
  };
  short* wtQKV = (short*)carve((size_t)8 * 3072 * 1024 * 2);
  short* wtP   = (short*)carve((size_t)8 * 1024 * 1024 * 2);
  short* wt1   = (short*)carve((size_t)8 * 4096 * 1024 * 2);
  short* wt2   = (short*)carve((size_t)8 * 1024 * 4096 * 2);
  float* x     = (float*)carve((size_t)2048 * 1024 * 4);
  short* h     = (short*)carve((size_t)2048 * 1024 * 2);
  short* qkv   = (short*)carve((size_t)2048 * 3072 * 2);
  short* y     = (short*)carve((size_t)2048 * 1024 * 2);
  short* hm    = (short*)carve((size_t)2048 * 4096 * 2);
  float* part  = (float*)carve((size_t)4 * 2048 * 1024 * 4);

  const size_t S1M = (size_t)1024 * 1024, S3M = (size_t)3072 * 1024,
               S4M = (size_t)4096 * 1024;

  wconv_all<<<dim3(768, 8), 256, 0, stream>>>(
      Wq, Wk, Wv, Wp, W1, W2, wtQKV, wtP, wt1, wt2);

  ln_kernel<<<2048, 256, 0, stream>>>(seq, ln1w, ln1b, h);

  for (int l = 0; l < 8; ++l){
    const float* xin = (l == 0) ? seq : x;
    // QKV: (24,32) = 768 blocks
    gemm5<0><<<dim3(24, 32, 1), 256, 0, stream>>>(
        h, wtQKV + l * S3M, qkv, bq + l * 1024, bk + l * 1024, bv + l * 1024,
        2048, 3072, 1024, 1024);
    attn_kernel<<<dim3(16, 16, 2), 256, 0, stream>>>(qkv, y);
    // P projection: split-K2 -> (8,32,2) = 512 blocks
    gemm5<3><<<dim3(8, 32, 2), 256, 0, stream>>>(
        y, wtP + l * S1M, part, nullptr, nullptr, nullptr,
        2048, 1024, 1024, 512);
    reduce_ln<2, false><<<2048, 256, 0, stream>>>(
        part, xin, bp + l * 1024, x, ln2w + l * 1024, ln2b + l * 1024, h);
    // MLP1: (32,32) = 1024 blocks
    gemm5<2><<<dim3(32, 32, 1), 256, 0, stream>>>(
        h, wt1 + l * S4M, hm, b1 + l * 4096, nullptr, nullptr,
        2048, 4096, 1024, 1024);
    // MLP2: split-K2 -> (8,32,2) = 512 blocks (halves partial traffic vs K4)
    gemm5<3><<<dim3(8, 32, 2), 256, 0, stream>>>(
        hm, wt2 + l * S4M, part, nullptr, nullptr, nullptr,
        2048, 1024, 4096, 2048);
    if (l < 7){
      reduce_ln<2, false><<<2048, 256, 0, stream>>>(
          part, x, b2 + l * 1024, x, ln1w + (l + 1) * 1024,
          ln1b + (l + 1) * 1024, h);
    } else {
      reduce_ln<2, true><<<2048, 256, 0, stream>>>(
          part, x, b2 + l * 1024, x, lnfw, lnfb, d_out);
    }
  }
}

// Round 18
// 1235.652 us; speedup vs baseline: 1.0615x; 1.0113x over previous
//
#include <hip/hip_runtime.h>
#include <cstdint>

#define DEVI __device__ __forceinline__

typedef short v8s __attribute__((ext_vector_type(8)));
typedef float v4f __attribute__((ext_vector_type(4)));

DEVI short f2bf(float f){
  uint32_t u = __builtin_bit_cast(uint32_t, f);
  u += 0x7FFF + ((u >> 16) & 1);          // round-to-nearest-even
  return (short)(u >> 16);
}
DEVI float bf2f(short s){
  uint32_t u = ((uint32_t)(uint16_t)s) << 16;
  return __builtin_bit_cast(float, u);
}
DEVI uint32_t pk2(float a, float b){
  return (uint32_t)(uint16_t)f2bf(a) | ((uint32_t)(uint16_t)f2bf(b) << 16);
}

DEVI void gload16(const void* g, void* l){
  __builtin_amdgcn_global_load_lds(
      (const __attribute__((address_space(1))) unsigned*)g,
      (__attribute__((address_space(3))) unsigned*)l, 16, 0, 0);
}

// ---------------------------------------------------------------- LayerNorm
__global__ __launch_bounds__(256) void ln_kernel(
    const float* __restrict__ x, const float* __restrict__ w,
    const float* __restrict__ b, void* __restrict__ out)
{
  const int row = blockIdx.x;
  const int t = threadIdx.x;
  const float4 v = ((const float4*)(x + (size_t)row * 1024))[t];
  float s  = v.x + v.y + v.z + v.w;
  float s2 = v.x*v.x + v.y*v.y + v.z*v.z + v.w*v.w;
  #pragma unroll
  for (int m = 1; m < 64; m <<= 1){ s += __shfl_xor(s, m); s2 += __shfl_xor(s2, m); }
  __shared__ float ps[4], ps2[4];
  if ((t & 63) == 0){ ps[t >> 6] = s; ps2[t >> 6] = s2; }
  __syncthreads();
  s  = ps[0] + ps[1] + ps[2] + ps[3];
  s2 = ps2[0] + ps2[1] + ps2[2] + ps2[3];
  const float mu = s * (1.f / 1024.f);
  const float rs = rsqrtf(s2 * (1.f / 1024.f) - mu * mu + 1e-5f);
  const float4 wv = ((const float4*)w)[t];
  const float4 bv = ((const float4*)b)[t];
  uint2 pk;
  pk.x = pk2((v.x - mu) * rs * wv.x + bv.x, (v.y - mu) * rs * wv.y + bv.y);
  pk.y = pk2((v.z - mu) * rs * wv.z + bv.z, (v.w - mu) * rs * wv.w + bv.w);
  ((uint2*)out)[(size_t)row * 256 + t] = pk;
}

// ------------- split-K reduce + residual + bias, fused with LayerNorm.
template<int S, bool FIN>
__global__ __launch_bounds__(256) void reduce_ln(
    const float* __restrict__ part, const float* __restrict__ resid,
    const float* __restrict__ bias, float* __restrict__ xout,
    const float* __restrict__ lw, const float* __restrict__ lb,
    void* __restrict__ hout)
{
  const int row = blockIdx.x;
  const int t = threadIdx.x;
  float4 v = ((const float4*)(resid + (size_t)row * 1024))[t];
  const float4 bz = ((const float4*)bias)[t];
  v.x += bz.x; v.y += bz.y; v.z += bz.z; v.w += bz.w;
  #pragma unroll
  for (int s = 0; s < S; ++s){
    const float4 pv = ((const float4*)(part + ((size_t)s * 2048 + row) * 1024))[t];
    v.x += pv.x; v.y += pv.y; v.z += pv.z; v.w += pv.w;
  }
  ((float4*)(xout + (size_t)row * 1024))[t] = v;
  float s  = v.x + v.y + v.z + v.w;
  float s2 = v.x*v.x + v.y*v.y + v.z*v.z + v.w*v.w;
  #pragma unroll
  for (int m = 1; m < 64; m <<= 1){ s += __shfl_xor(s, m); s2 += __shfl_xor(s2, m); }
  __shared__ float ps[4], ps2[4];
  if ((t & 63) == 0){ ps[t >> 6] = s; ps2[t >> 6] = s2; }
  __syncthreads();
  s  = ps[0] + ps[1] + ps[2] + ps[3];
  s2 = ps2[0] + ps2[1] + ps2[2] + ps2[3];
  const float mu = s * (1.f / 1024.f);
  const float rs = rsqrtf(s2 * (1.f / 1024.f) - mu * mu + 1e-5f);
  const float4 wv = ((const float4*)lw)[t];
  const float4 bv = ((const float4*)lb)[t];
  const float o0 = (v.x - mu) * rs * wv.x + bv.x;
  const float o1 = (v.y - mu) * rs * wv.y + bv.y;
  const float o2 = (v.z - mu) * rs * wv.z + bv.z;
  const float o3 = (v.w - mu) * rs * wv.w + bv.w;
  if (FIN){
    ((float4*)hout)[(size_t)row * 256 + t] = make_float4(o0, o1, o2, o3);
  } else {
    uint2 pk;
    pk.x = pk2(o0, o1);
    pk.y = pk2(o2, o3);
    ((uint2*)hout)[(size_t)row * 256 + t] = pk;
  }
}

// ---------------- all weights fp32[K][N] -> bf16[N][K] in ONE dispatch.
// 64n x 128k tiles (34 KB LDS -> 4 blocks/CU for more outstanding NT
// streams) + non-temporal loads/stores (R17-verified: 2.7 -> 3.7 TB/s).
// grid = (1536, 8): y = layer, x = job id.
__global__ __launch_bounds__(256) void wconv_all(
    const float* __restrict__ Wq, const float* __restrict__ Wk,
    const float* __restrict__ Wv, const float* __restrict__ Wp,
    const float* __restrict__ W1, const float* __restrict__ W2,
    short* __restrict__ wtQKV, short* __restrict__ wtP,
    short* __restrict__ wt1, short* __restrict__ wt2)
{
  const int j = blockIdx.x;
  const size_t l = blockIdx.y;
  const size_t S1M = 1048576, S3M = 3145728, S4M = 4194304;
  const float* W; short* Wt; int K, N, n0, k0;
  if (j < 512){
    const int which = j >> 7, jj = j & 127;     // 16n x 8kc
    n0 = (jj & 15) * 64; k0 = (jj >> 4) * 128; K = 1024; N = 1024;
    if (which == 0){ W = Wq + l * S1M; Wt = wtQKV + l * S3M; }
    else if (which == 1){ W = Wk + l * S1M; Wt = wtQKV + l * S3M + S1M; }
    else if (which == 2){ W = Wv + l * S1M; Wt = wtQKV + l * S3M + 2 * S1M; }
    else { W = Wp + l * S1M; Wt = wtP + l * S1M; }
  } else if (j < 1024){
    const int jj = j - 512;                     // 64n x 8kc
    n0 = (jj & 63) * 64; k0 = (jj >> 6) * 128; K = 1024; N = 4096;
    W = W1 + l * S4M; Wt = wt1 + l * S4M;
  } else {
    const int jj = j - 1024;                    // 16n x 32kc
    n0 = (jj & 15) * 64; k0 = (jj >> 4) * 128; K = 4096; N = 1024;
    W = W2 + l * S4M; Wt = wt2 + l * S4M;
  }
  __shared__ float st[64][65];
  __shared__ short tb[64 * 136];                // [n][k 128+8 pad]
  const int tid = threadIdx.x;
  const int c4 = (tid & 15) * 4, r = tid >> 4;  // staging coords
  const int nn = tid >> 3, k8 = (tid & 7) * 8;  // transpose coords

  #pragma unroll
  for (int sub = 0; sub < 2; ++sub){
    const int ks = k0 + sub * 64;
    #pragma unroll
    for (int i = 0; i < 4; ++i){
      const v4f v = __builtin_nontemporal_load(
          (const v4f*)(W + (size_t)(ks + r + i*16) * N + n0 + c4));
      st[r + i*16][c4 + 0] = v[0];
      st[r + i*16][c4 + 1] = v[1];
      st[r + i*16][c4 + 2] = v[2];
      st[r + i*16][c4 + 3] = v[3];
    }
    __syncthreads();
    #pragma unroll
    for (int half = 0; half < 2; ++half){
      const int n = nn + half * 32;
      v8s s;
      #pragma unroll
      for (int q = 0; q < 8; ++q) s[q] = f2bf(st[k8 + q][n]);
      *(v8s*)(tb + n * 136 + sub * 64 + k8) = s;
    }
    __syncthreads();
  }
  // write phase: 64 rows x 256B contiguous segments, non-temporal
  #pragma unroll
  for (int p = 0; p < 4; ++p){
    const int flat = tid + p * 256;
    const int n = flat >> 4, kseg = (flat & 15) * 8;
    const v8s s = *(const v8s*)(tb + n * 136 + kseg);
    __builtin_nontemporal_store(s, (v8s*)(Wt + (size_t)(n0 + n) * K + k0 + kseg));
  }
}

// ---------------------------------------------------------------- GEMM 64x128
// R13-verified operating point (FROZEN): 256 thr = 4 waves (2x2 of 32x64 out),
// SINGLE-buffer 24.6 KB LDS, 4 blocks/CU; loop = sync; stage; sync; compute.
// Latency hiding from co-resident blocks (m114). n-fastest XCD chunks (T1);
// T2 XOR-swizzle. Split-K via z (EPI 3 -> fp32 partials).
template<int EPI>
__global__ __launch_bounds__(256, 4) void gemm5(
    const short* __restrict__ A, const short* __restrict__ Bt,
    void* __restrict__ out,
    const float* __restrict__ b0, const float* __restrict__ b1,
    const float* __restrict__ b2, int M, int N, int K, int kchunk)
{
  __shared__ __attribute__((aligned(16))) short a_t[64 * 64];
  __shared__ __attribute__((aligned(16))) short b_t[128 * 64];
  const int tid = threadIdx.x, l = tid & 63, w = tid >> 6;

  const int gx = gridDim.x;
  const int bid = blockIdx.y * gx + blockIdx.x;
  const int cpx = (gx * gridDim.y) >> 3;
  const int swz = (bid & 7) * cpx + (bid >> 3);
  const int m0 = (swz / gx) * 64, n0 = (swz % gx) * 128;
  const int kt0 = blockIdx.z * kchunk;

  const int lr = l >> 3;                        // staging row within 8-group
  const int scol = ((l & 7) * 16) ^ (lr << 4);  // pre-swizzled source byte col
  const int wm = w >> 1, wn = w & 1;            // wave grid 2x2
  const int fr = l & 15;
  const int rg = l >> 4;
  const int rxor = (fr & 7) << 4;               // read-side XOR (bytes)

  const v4f vz = {0.f, 0.f, 0.f, 0.f};
  v4f acc[2][4];
  #pragma unroll
  for (int i = 0; i < 2; ++i)
    #pragma unroll
    for (int j = 0; j < 4; ++j) acc[i][j] = vz;

  const char* Ab = (const char*)A;
  const char* Bb = (const char*)Bt;
  auto stage = [&](int kt){
    #pragma unroll
    for (int j = 0; j < 2; ++j){                // A: 16 rows per wave
      const int rb = w * 16 + j * 8;
      gload16(Ab + ((size_t)(m0 + rb + lr) * K + kt) * 2 + scol,
              (char*)a_t + rb * 128);
    }
    #pragma unroll
    for (int j = 0; j < 4; ++j){                // B: 32 rows per wave
      const int rb = w * 32 + j * 8;
      gload16(Bb + ((size_t)(n0 + rb + lr) * K + kt) * 2 + scol,
              (char*)b_t + rb * 128);
    }
  };

  const int NT = kchunk >> 6;
  for (int t = 0; t < NT; ++t){
    __syncthreads();                  // prior step's LDS reads complete
    stage(kt0 + (t << 6));
    __syncthreads();                  // implicit vmcnt(0): tile resident
    __builtin_amdgcn_s_setprio(1);
    #pragma unroll
    for (int ks = 0; ks < 2; ++ks){
      const int co = ks * 64 + rg * 16;
      v8s af[2], bf[4];
      #pragma unroll
      for (int mf = 0; mf < 2; ++mf)
        af[mf] = *(const v8s*)((char*)a_t + (wm * 32 + mf * 16 + fr) * 128
                               + (co ^ rxor));
      #pragma unroll
      for (int nf = 0; nf < 4; ++nf)
        bf[nf] = *(const v8s*)((char*)b_t + (wn * 64 + nf * 16 + fr) * 128
                               + (co ^ rxor));
      #pragma unroll
      for (int mf = 0; mf < 2; ++mf)
        #pragma unroll
        for (int nf = 0; nf < 4; ++nf)
          acc[mf][nf] = __builtin_amdgcn_mfma_f32_16x16x32_bf16(
              af[mf], bf[nf], acc[mf][nf], 0, 0, 0);
    }
    __builtin_amdgcn_s_setprio(0);
  }

  float* outp = (EPI == 3)
      ? (float*)out + (size_t)blockIdx.z * ((size_t)M * N) : (float*)out;
  #pragma unroll
  for (int mf = 0; mf < 2; ++mf){
    #pragma unroll
    for (int nf = 0; nf < 4; ++nf){
      const int col = n0 + wn * 64 + nf * 16 + fr;
      float bias = 0.f;
      if (EPI == 0)
        bias = col < 1024 ? b0[col] : (col < 2048 ? b1[col - 1024] : b2[col - 2048]);
      else if (EPI == 2)
        bias = b0[col];
      #pragma unroll
      for (int r = 0; r < 4; ++r){
        const int row = m0 + wm * 32 + mf * 16 + rg * 4 + r;
        const float v = acc[mf][nf][r] + bias;
        if (EPI == 0){
          ((short*)out)[(size_t)row * N + col] = f2bf(v);
        } else if (EPI == 2){
          const float g = 0.5f * v * (1.0f + erff(v * 0.70710678118f));
          ((short*)out)[(size_t)row * N + col] = f2bf(g);
        } else {
          outp[(size_t)row * N + col] = v;
        }
      }
    }
  }
}

// ---------------------------------------------------------------- Attention
// Swapped-operand flash attention + register prefetch + complementary-qb
// makespan balance (R13-verified, FROZEN).
__global__ __launch_bounds__(256) void attn_kernel(
    const short* __restrict__ qkv, short* __restrict__ y)
{
  const int hh = blockIdx.y, b = blockIdx.z;
  const int qb = b ? 15 - blockIdx.x : blockIdx.x;
  const int tid = threadIdx.x, l = tid & 63, w = tid >> 6;
  __shared__ __attribute__((aligned(16))) short vt[2][64 * 72];   // V^T [d][s]
  __shared__ __attribute__((aligned(16))) short pl[4][16 * 72];   // P [q][k]

  const int fr = l & 15;
  const int rg = l >> 4;
  const int fko = rg * 8;
  const float qs = 0.125f * 1.44269504088896f;   // 1/sqrt(64) * log2(e)
  const v4f vz = {0.f, 0.f, 0.f, 0.f};
  const int vd0 = (tid & 7) * 8, vs0 = (tid >> 3) * 2;
  const short* kbase = qkv + (size_t)(b * 1024) * 3072 + 1024 + hh * 64 + fko;

  const size_t qrow = (size_t)(b * 1024 + qb * 64 + w * 16 + fr) * 3072
                      + hh * 64 + fko;
  v8s qf0, qf1;
  {
    const v8s q0 = *(const v8s*)(qkv + qrow);
    const v8s q1 = *(const v8s*)(qkv + qrow + 32);
    #pragma unroll
    for (int j = 0; j < 8; ++j){
      qf0[j] = f2bf(bf2f(q0[j]) * qs);
      qf1[j] = f2bf(bf2f(q1[j]) * qs);
    }
  }

  v4f o[4] = {vz, vz, vz, vz};
  float mrow = -1e30f, lrow = 0.f;

  auto loadK = [&](int kvb, v8s (&kk)[4][2]){
    #pragma unroll
    for (int nf = 0; nf < 4; ++nf){
      const short* kp = kbase + (size_t)(kvb * 64 + nf * 16 + fr) * 3072;
      kk[nf][0] = *(const v8s*)kp;
      kk[nf][1] = *(const v8s*)(kp + 32);
    }
  };
  auto loadV = [&](int kvb, v8s& r0, v8s& r1){
    const short* vsrc = qkv + (size_t)(b * 1024 + kvb * 64 + vs0) * 3072
                        + 2048 + hh * 64 + vd0;
    r0 = *(const v8s*)vsrc;
    r1 = *(const v8s*)(vsrc + 3072);
  };

  v8s kc[4][2], kn[4][2], vc0, vc1, vn0, vn1;
  loadK(0, kc);
  loadV(0, vc0, vc1);

  for (int kvb = 0; kvb <= qb; ++kvb){
    short* vcur = vt[kvb & 1];
    #pragma unroll
    for (int j = 0; j < 8; ++j){
      const uint32_t pk = (uint16_t)vc0[j] | ((uint32_t)(uint16_t)vc1[j] << 16);
      *(uint32_t*)(vcur + (vd0 + j) * 72 + vs0) = pk;
    }
    __syncthreads();
    if (kvb < qb){ loadK(kvb + 1, kn); loadV(kvb + 1, vn0, vn1); }

    v4f s[4] = {vz, vz, vz, vz};
    __builtin_amdgcn_s_setprio(1);
    #pragma unroll
    for (int nf = 0; nf < 4; ++nf){
      s[nf] = __builtin_amdgcn_mfma_f32_16x16x32_bf16(kc[nf][0], qf0, s[nf], 0, 0, 0);
      s[nf] = __builtin_amdgcn_mfma_f32_16x16x32_bf16(kc[nf][1], qf1, s[nf], 0, 0, 0);
    }
    __builtin_amdgcn_s_setprio(0);

    float pmax = s[0][0];
    #pragma unroll
    for (int nf = 0; nf < 4; ++nf)
      #pragma unroll
      for (int r = 0; r < 4; ++r) pmax = fmaxf(pmax, s[nf][r]);
    pmax = fmaxf(pmax, __shfl_xor(pmax, 16));
    pmax = fmaxf(pmax, __shfl_xor(pmax, 32));
    const float mn = fmaxf(mrow, pmax);
    const float fac = exp2f(mrow - mn);
    float rs = 0.f;
    #pragma unroll
    for (int nf = 0; nf < 4; ++nf)
      #pragma unroll
      for (int r = 0; r < 4; ++r){
        s[nf][r] = exp2f(s[nf][r] - mn);
        rs += s[nf][r];
      }
    rs += __shfl_xor(rs, 16);
    rs += __shfl_xor(rs, 32);
    lrow = lrow * fac + rs;
    mrow = mn;
    #pragma unroll
    for (int nf = 0; nf < 4; ++nf)
      #pragma unroll
      for (int r = 0; r < 4; ++r) o[nf][r] *= fac;

    #pragma unroll
    for (int nf = 0; nf < 4; ++nf){
      uint2 pk;
      pk.x = pk2(s[nf][0], s[nf][1]);
      pk.y = pk2(s[nf][2], s[nf][3]);
      *(uint2*)(pl[w] + fr * 72 + nf * 16 + rg * 4) = pk;
    }

    __builtin_amdgcn_s_setprio(1);
    #pragma unroll
    for (int ks = 0; ks < 2; ++ks){
      const v8s pa = *(const v8s*)(pl[w] + fr * 72 + ks * 32 + fko);
      #pragma unroll
      for (int nf = 0; nf < 4; ++nf){
        const v8s vb = *(const v8s*)(vcur + (nf * 16 + fr) * 72 + ks * 32 + fko);
        o[nf] = __builtin_amdgcn_mfma_f32_16x16x32_bf16(vb, pa, o[nf], 0, 0, 0);
      }
    }
    __builtin_amdgcn_s_setprio(0);

    if (kvb < qb){
      #pragma unroll
      for (int nf = 0; nf < 4; ++nf){ kc[nf][0] = kn[nf][0]; kc[nf][1] = kn[nf][1]; }
      vc0 = vn0; vc1 = vn1;
    }
  }

  const float inv = 1.0f / lrow;
  const size_t orow = (size_t)(b * 1024 + qb * 64 + w * 16 + fr) * 1024 + hh * 64;
  #pragma unroll
  for (int nf = 0; nf < 4; ++nf){
    short4 sv;
    sv.x = f2bf(o[nf][0] * inv);
    sv.y = f2bf(o[nf][1] * inv);
    sv.z = f2bf(o[nf][2] * inv);
    sv.w = f2bf(o[nf][3] * inv);
    *(short4*)(y + orow + nf * 16 + rg * 4) = sv;
  }
}

// ---------------------------------------------------------------- launch
extern "C" void kernel_launch(void* const* d_in, const int* in_sizes, int n_in,
                              void* d_out, int out_size, void* d_ws, size_t ws_size,
                              hipStream_t stream)
{
  const float* seq  = (const float*)d_in[0];
  const float* ln1w = (const float*)d_in[1];
  const float* ln1b = (const float*)d_in[2];
  const float* Wq   = (const float*)d_in[3];
  const float* bq   = (const float*)d_in[4];
  const float* Wk   = (const float*)d_in[5];
  const float* bk   = (const float*)d_in[6];
  const float* Wv   = (const float*)d_in[7];
  const float* bv   = (const float*)d_in[8];
  const float* Wp   = (const float*)d_in[9];
  const float* bp   = (const float*)d_in[10];
  const float* ln2w = (const float*)d_in[11];
  const float* ln2b = (const float*)d_in[12];
  const float* W1   = (const float*)d_in[13];
  const float* b1   = (const float*)d_in[14];
  const float* W2   = (const float*)d_in[15];
  const float* b2   = (const float*)d_in[16];
  const float* lnfw = (const float*)d_in[17];
  const float* lnfb = (const float*)d_in[18];

  char* p = (char*)d_ws;
  auto carve = [&](size_t bytes){
    void* r = (void*)p;
    p += (bytes + 255) & ~(size_t)255;
    return r;
  };
  short* wtQKV = (short*)carve((size_t)8 * 3072 * 1024 * 2);
  short* wtP   = (short*)carve((size_t)8 * 1024 * 1024 * 2);
  short* wt1   = (short*)carve((size_t)8 * 4096 * 1024 * 2);
  short* wt2   = (short*)carve((size_t)8 * 1024 * 4096 * 2);
  float* x     = (float*)carve((size_t)2048 * 1024 * 4);
  short* h     = (short*)carve((size_t)2048 * 1024 * 2);
  short* qkv   = (short*)carve((size_t)2048 * 3072 * 2);
  short* y     = (short*)carve((size_t)2048 * 1024 * 2);
  short* hm    = (short*)carve((size_t)2048 * 4096 * 2);
  float* part  = (float*)carve((size_t)4 * 2048 * 1024 * 4);

  const size_t S1M = (size_t)1024 * 1024, S3M = (size_t)3072 * 1024,
               S4M = (size_t)4096 * 1024;

  wconv_all<<<dim3(1536, 8), 256, 0, stream>>>(
      Wq, Wk, Wv, Wp, W1, W2, wtQKV, wtP, wt1, wt2);

  ln_kernel<<<2048, 256, 0, stream>>>(seq, ln1w, ln1b, h);

  for (int l = 0; l < 8; ++l){
    const float* xin = (l == 0) ? seq : x;
    // QKV: (24,32) = 768 blocks
    gemm5<0><<<dim3(24, 32, 1), 256, 0, stream>>>(
        h, wtQKV + l * S3M, qkv, bq + l * 1024, bk + l * 1024, bv + l * 1024,
        2048, 3072, 1024, 1024);
    attn_kernel<<<dim3(16, 16, 2), 256, 0, stream>>>(qkv, y);
    // P projection: split-K2 -> (8,32,2) = 512 blocks
    gemm5<3><<<dim3(8, 32, 2), 256, 0, stream>>>(
        y, wtP + l * S1M, part, nullptr, nullptr, nullptr,
        2048, 1024, 1024, 512);
    reduce_ln<2, false><<<2048, 256, 0, stream>>>(
        part, xin, bp + l * 1024, x, ln2w + l * 1024, ln2b + l * 1024, h);
    // MLP1: (32,32) = 1024 blocks
    gemm5<2><<<dim3(32, 32, 1), 256, 0, stream>>>(
        h, wt1 + l * S4M, hm, b1 + l * 4096, nullptr, nullptr,
        2048, 4096, 1024, 1024);
    // MLP2: split-K4 -> (8,32,4) = 1024 blocks (R13-verified 4/CU point)
    gemm5<3><<<dim3(8, 32, 4), 256, 0, stream>>>(
        hm, wt2 + l * S4M, part, nullptr, nullptr, nullptr,
        2048, 1024, 4096, 1024);
    if (l < 7){
      reduce_ln<4, false><<<2048, 256, 0, stream>>>(
          part, x, b2 + l * 1024, x, ln1w + (l + 1) * 1024,
          ln1b + (l + 1) * 1024, h);
    } else {
      reduce_ln<4, true><<<2048, 256, 0, stream>>>(
          part, x, b2 + l * 1024, x, lnfw, lnfb, d_out);
    }
  }
}